// Round 5
// baseline (202.266 us; speedup 1.0000x reference)
//
#include <hip/hip_runtime.h>

// Problem constants
#define NB 8
#define NS 256
#define ND 64
#define NV 8192
#define CH 16       // s-chunk per bilinear block
#define BT_TILE 16  // bt rows per logits block
#define NCHUNK 2176 // sum over t of (t/16 + 1)

typedef float f32x4 __attribute__((ext_vector_type(4)));

// h[b,s,d] = embed[x[b,s], d]  and  y = 0   (131072 threads exactly)
__global__ __launch_bounds__(256) void k_init(const int* __restrict__ x,
                                              const float* __restrict__ embed,
                                              float* __restrict__ h,
                                              float* __restrict__ y) {
    int tid = blockIdx.x * 256 + threadIdx.x;
    int bs = tid >> 6;
    int d  = tid & 63;
    h[tid] = embed[(size_t)x[bs] * ND + d];
    y[tid] = 0.f;
}

// et[o][v] = embed[v][o]
__global__ __launch_bounds__(256) void k_transpose(const float* __restrict__ embed,
                                                   float* __restrict__ et) {
    __shared__ float tile[64][65];
    int vbase = blockIdx.x * 64;
    int o = threadIdx.x & 63;
    int r = threadIdx.x >> 6;  // 0..3
    for (int i = r; i < 64; i += 4)
        tile[i][o] = embed[(size_t)(vbase + i) * ND + o];
    __syncthreads();
    for (int i = r; i < 64; i += 4)
        et[(size_t)i * NV + vbase + o] = tile[o][i];
}

// y[b,t,o] += sum_{s in chunk, s<=t} sum_d h[b,s,d] * K[t,s,d,o]
// Exact triangular launch, longest-job-first (t descending).
__global__ __launch_bounds__(256) void k_bilinear(const float* __restrict__ h,
                                                  const float* __restrict__ K,
                                                  float* __restrict__ y) {
    // decode chunk id -> (t, c); L descending in t so blockIdx.x=0 is biggest
    int L = (NCHUNK - 1) - (int)blockIdx.x;
    int g = 0;
    while (8 * (g + 1) * (g + 2) <= L) g++;       // group g = t>>4, 16(g+1) chunks/group
    int rem = L - 8 * g * (g + 1);
    int tq  = rem / (g + 1);
    int t   = 16 * g + tq;
    int c   = rem - tq * (g + 1);
    int s0  = c * CH;
    int ns  = min(t + 1 - s0, CH);

    __shared__ float smem[NB * CH * ND]; // 32 KB; reused for reduction

    // stage h[b, s0:s0+CH, :] -> LDS (contiguous per b, fully coalesced)
    for (int i = threadIdx.x; i < NB * CH * ND; i += 256) {
        int b    = i >> 10;       // / (CH*ND)
        int rem2 = i & 1023;
        smem[i] = h[((size_t)b * NS + s0) * ND + rem2];
    }
    __syncthreads();

    int ot = threadIdx.x & 15;   // o-quad index
    int dg = threadIdx.x >> 4;   // d-group 0..15
    int o4 = ot * 4;
    int db = dg * 4;

    f32x4 acc[NB];
#pragma unroll
    for (int b = 0; b < NB; b++) acc[b] = (f32x4)(0.f);

    const float* Kt = K + (size_t)t * NS * ND * ND;
    if (ns == CH) {
        // compile-time trip count, moderate unroll: ~16 loads in flight
#pragma unroll 4
        for (int si = 0; si < CH; si++) {
            const float* Ks = Kt + (size_t)(s0 + si) * ND * ND;
#pragma unroll
            for (int i = 0; i < 4; i++) {
                int d = db + i;
                f32x4 k4 = *reinterpret_cast<const f32x4*>(Ks + d * ND + o4);
#pragma unroll
                for (int b = 0; b < NB; b++) {
                    float hv = smem[b * (CH * ND) + si * ND + d];
                    acc[b] += hv * k4;
                }
            }
        }
    } else {
        for (int si = 0; si < ns; si++) {
            const float* Ks = Kt + (size_t)(s0 + si) * ND * ND;
#pragma unroll
            for (int i = 0; i < 4; i++) {
                int d = db + i;
                f32x4 k4 = *reinterpret_cast<const f32x4*>(Ks + d * ND + o4);
#pragma unroll
                for (int b = 0; b < NB; b++) {
                    float hv = smem[b * (CH * ND) + si * ND + d];
                    acc[b] += hv * k4;
                }
            }
        }
    }
    __syncthreads();

    // reduce the 16 d-groups via LDS, then atomic into y
    f32x4* red = reinterpret_cast<f32x4*>(smem);
#pragma unroll
    for (int b = 0; b < NB; b++) red[(dg * NB + b) * 16 + ot] = acc[b];
    __syncthreads();

    if (threadIdx.x < 128) {
        int b = threadIdx.x >> 4;
        int o = threadIdx.x & 15;
        f32x4 s = (f32x4)(0.f);
#pragma unroll
        for (int gg = 0; gg < 16; gg++)
            s += red[(gg * NB + b) * 16 + o];
        float* yp = y + ((size_t)b * NS + t) * ND + o * 4;
        atomicAdd(yp + 0, s.x);
        atomicAdd(yp + 1, s.y);
        atomicAdd(yp + 2, s.z);
        atomicAdd(yp + 3, s.w);
    }
}

// out[bt, v] = sum_o y[bt, o] * et[o][v]
__global__ __launch_bounds__(256) void k_logits(const float* __restrict__ y,
                                                const float* __restrict__ et,
                                                float* __restrict__ out) {
    int bt0 = blockIdx.x * BT_TILE;
    int v4  = blockIdx.y * 1024 + threadIdx.x * 4;

    __shared__ float ylds[BT_TILE][ND];
    for (int i = threadIdx.x; i < BT_TILE * ND; i += 256)
        ylds[i >> 6][i & 63] = y[(size_t)bt0 * ND + i];
    __syncthreads();

    f32x4 acc[BT_TILE];
#pragma unroll
    for (int r = 0; r < BT_TILE; r++) acc[r] = (f32x4)(0.f);

#pragma unroll 4
    for (int o = 0; o < ND; o++) {
        f32x4 e4 = *reinterpret_cast<const f32x4*>(et + (size_t)o * NV + v4);
#pragma unroll
        for (int r = 0; r < BT_TILE; r++) {
            float yv = ylds[r][o];
            acc[r] += yv * e4;
        }
    }

#pragma unroll
    for (int r = 0; r < BT_TILE; r++)
        __builtin_nontemporal_store(acc[r],
            reinterpret_cast<f32x4*>(out + (size_t)(bt0 + r) * NV + v4));
}

extern "C" void kernel_launch(void* const* d_in, const int* in_sizes, int n_in,
                              void* d_out, int out_size, void* d_ws, size_t ws_size,
                              hipStream_t stream) {
    const int*   x     = (const int*)d_in[0];
    const float* embed = (const float*)d_in[1];
    const float* K     = (const float*)d_in[2];
    float* out = (float*)d_out;

    float* h  = (float*)d_ws;          // 131072 f32 (512 KB)
    float* y  = h + NB * NS * ND;      // 131072 f32 (512 KB)
    float* et = y + NB * NS * ND;      // 524288 f32 (2 MB)

    k_init<<<dim3((NB * NS * ND) / 256), 256, 0, stream>>>(x, embed, h, y);
    k_transpose<<<dim3(NV / 64), 256, 0, stream>>>(embed, et);
    k_bilinear<<<dim3(NCHUNK), 256, 0, stream>>>(h, K, y);
    k_logits<<<dim3((NB * NS) / BT_TILE, NV / 1024), 256, 0, stream>>>(y, et, out);
}

// Round 6
// 149.756 us; speedup vs baseline: 1.3506x; 1.3506x over previous
//
#include <hip/hip_runtime.h>

// Problem constants
#define NB 8
#define NS 256
#define ND 64
#define NV 8192
#define CH 16       // s-chunk per bilinear block
#define NCHUNK 2176 // sum over t of (t/16 + 1)

typedef float f32x4 __attribute__((ext_vector_type(4)));
typedef short s16x4 __attribute__((ext_vector_type(4)));
typedef short s16x8 __attribute__((ext_vector_type(8)));

__device__ __forceinline__ short f2bf(float x) {
    union { float f; unsigned u; } v; v.f = x;
    unsigned u = v.u + 0x7FFFu + ((v.u >> 16) & 1u);  // RNE
    return (short)(u >> 16);
}

__device__ __forceinline__ s16x8 cvt8(f32x4 lo, f32x4 hi) {
    s16x8 r;
    r[0] = f2bf(lo.x); r[1] = f2bf(lo.y); r[2] = f2bf(lo.z); r[3] = f2bf(lo.w);
    r[4] = f2bf(hi.x); r[5] = f2bf(hi.y); r[6] = f2bf(hi.z); r[7] = f2bf(hi.w);
    return r;
}

// h[b,s,d] = embed[x[b,s], d]  and  y = 0   (131072 threads exactly)
__global__ __launch_bounds__(256) void k_init(const int* __restrict__ x,
                                              const float* __restrict__ embed,
                                              float* __restrict__ h,
                                              float* __restrict__ y) {
    int tid = blockIdx.x * 256 + threadIdx.x;
    int bs = tid >> 6;
    int d  = tid & 63;
    h[tid] = embed[(size_t)x[bs] * ND + d];
    y[tid] = 0.f;
}

// eb[v][o] = bf16(embed[v][o])   (row-major, feeds MFMA B-frags directly)
__global__ __launch_bounds__(256) void k_cast(const float* __restrict__ embed,
                                              short* __restrict__ eb) {
    int tid = blockIdx.x * 256 + threadIdx.x;
    f32x4 v = *reinterpret_cast<const f32x4*>(embed + (size_t)tid * 4);
    s16x4 o;
    o.x = f2bf(v.x); o.y = f2bf(v.y); o.z = f2bf(v.z); o.w = f2bf(v.w);
    *reinterpret_cast<s16x4*>(eb + (size_t)tid * 4) = o;
}

// y[b,t,o] += sum_{s in chunk, s<=t} sum_d h[b,s,d] * K[t,s,d,o]
// Exact triangular launch, longest-job-first (t descending). R3-proven config.
__global__ __launch_bounds__(256) void k_bilinear(const float* __restrict__ h,
                                                  const float* __restrict__ K,
                                                  float* __restrict__ y) {
    int L = (NCHUNK - 1) - (int)blockIdx.x;
    int g = 0;
    while (8 * (g + 1) * (g + 2) <= L) g++;       // group g = t>>4
    int rem = L - 8 * g * (g + 1);
    int tq  = rem / (g + 1);
    int t   = 16 * g + tq;
    int c   = rem - tq * (g + 1);
    int s0  = c * CH;
    int ns  = min(t + 1 - s0, CH);

    __shared__ float smem[NB * CH * ND]; // 32 KB; reused for reduction

    for (int i = threadIdx.x; i < NB * CH * ND; i += 256) {
        int b    = i >> 10;
        int rem2 = i & 1023;
        smem[i] = h[((size_t)b * NS + s0) * ND + rem2];
    }
    __syncthreads();

    int ot = threadIdx.x & 15;   // o-quad index
    int dg = threadIdx.x >> 4;   // d-group 0..15
    int o4 = ot * 4;
    int db = dg * 4;

    f32x4 acc[NB];
#pragma unroll
    for (int b = 0; b < NB; b++) acc[b] = (f32x4)(0.f);

    const float* Kt = K + (size_t)t * NS * ND * ND;
    for (int si = 0; si < ns; si++) {
        const float* Ks = Kt + (size_t)(s0 + si) * ND * ND;
#pragma unroll
        for (int i = 0; i < 4; i++) {
            int d = db + i;
            f32x4 k4 = __builtin_nontemporal_load(
                reinterpret_cast<const f32x4*>(Ks + d * ND + o4));
#pragma unroll
            for (int b = 0; b < NB; b++) {
                float hv = smem[b * (CH * ND) + si * ND + d];
                acc[b] += hv * k4;
            }
        }
    }
    __syncthreads();

    f32x4* red = reinterpret_cast<f32x4*>(smem);
#pragma unroll
    for (int b = 0; b < NB; b++) red[(dg * NB + b) * 16 + ot] = acc[b];
    __syncthreads();

    if (threadIdx.x < 128) {
        int b = threadIdx.x >> 4;
        int o = threadIdx.x & 15;
        f32x4 s = (f32x4)(0.f);
#pragma unroll
        for (int gg = 0; gg < 16; gg++)
            s += red[(gg * NB + b) * 16 + o];
        float* yp = y + ((size_t)b * NS + t) * ND + o * 4;
        atomicAdd(yp + 0, s.x);
        atomicAdd(yp + 1, s.y);
        atomicAdd(yp + 2, s.z);
        atomicAdd(yp + 3, s.w);
    }
}

// out[bt, v] = sum_o y[bt, o] * E[v, o]  via bf16 MFMA (16x16x32, K=o)
// Block: 16 bt-rows x 1024 v-cols; 4 waves, wave w covers v-range w*256.
__global__ __launch_bounds__(256) void k_logits_mfma(const float* __restrict__ y,
                                                     const short* __restrict__ eb,
                                                     float* __restrict__ out) {
    int bt0  = blockIdx.x * 16;
    int wave = threadIdx.x >> 6;
    int lane = threadIdx.x & 63;
    int m    = lane & 15;      // A row / B col / D col
    int kg   = lane >> 4;      // k-group of 8
    int vb0  = blockIdx.y * 1024 + wave * 256;

    // A-frags: y[bt0+m][kg*8 + j] (fp32 -> bf16), two K-halves
    const float* yrow = y + (size_t)(bt0 + m) * ND + kg * 8;
    f32x4 p0 = *reinterpret_cast<const f32x4*>(yrow);
    f32x4 p1 = *reinterpret_cast<const f32x4*>(yrow + 4);
    f32x4 p2 = *reinterpret_cast<const f32x4*>(yrow + 32);
    f32x4 p3 = *reinterpret_cast<const f32x4*>(yrow + 36);
    s16x8 a0 = cvt8(p0, p1);
    s16x8 a1 = cvt8(p2, p3);

    for (int nt = 0; nt < 16; nt++) {
        int v0 = vb0 + nt * 16;
        const short* erow = eb + (size_t)(v0 + m) * ND + kg * 8;
        s16x8 b0 = *reinterpret_cast<const s16x8*>(erow);
        s16x8 b1 = *reinterpret_cast<const s16x8*>(erow + 32);
        f32x4 cacc = (f32x4)(0.f);
        cacc = __builtin_amdgcn_mfma_f32_16x16x32_bf16(a0, b0, cacc, 0, 0, 0);
        cacc = __builtin_amdgcn_mfma_f32_16x16x32_bf16(a1, b1, cacc, 0, 0, 0);
        // D: col = m, row = kg*4 + r
        float* op = out + (size_t)(bt0 + kg * 4) * NV + v0 + m;
#pragma unroll
        for (int r = 0; r < 4; r++)
            __builtin_nontemporal_store(cacc[r], op + (size_t)r * NV);
    }
}

extern "C" void kernel_launch(void* const* d_in, const int* in_sizes, int n_in,
                              void* d_out, int out_size, void* d_ws, size_t ws_size,
                              hipStream_t stream) {
    const int*   x     = (const int*)d_in[0];
    const float* embed = (const float*)d_in[1];
    const float* K     = (const float*)d_in[2];
    float* out = (float*)d_out;

    float* h  = (float*)d_ws;          // 131072 f32 (512 KB)
    float* y  = h + NB * NS * ND;      // 131072 f32 (512 KB)
    short* eb = (short*)(y + NB * NS * ND); // 524288 bf16 (1 MB)

    k_init<<<dim3((NB * NS * ND) / 256), 256, 0, stream>>>(x, embed, h, y);
    k_cast<<<dim3((NV * ND) / 1024), 256, 0, stream>>>(embed, eb);
    k_bilinear<<<dim3(NCHUNK), 256, 0, stream>>>(h, K, y);
    k_logits_mfma<<<dim3((NB * NS) / 16, NV / 1024), 256, 0, stream>>>(y, eb, out);
}

// Round 7
// 139.429 us; speedup vs baseline: 1.4507x; 1.0741x over previous
//
#include <hip/hip_runtime.h>

// Problem constants
#define NB 8
#define NS 256
#define ND 64
#define NV 8192
#define CH 16       // s-chunk per bilinear block
#define NCHUNK 2176 // sum over t of (t/16 + 1)

typedef float f32x4 __attribute__((ext_vector_type(4)));
typedef short s16x4 __attribute__((ext_vector_type(4)));
typedef short s16x8 __attribute__((ext_vector_type(8)));

__device__ __forceinline__ short f2bf(float x) {
    union { float f; unsigned u; } v; v.f = x;
    unsigned u = v.u + 0x7FFFu + ((v.u >> 16) & 1u);  // RNE
    return (short)(u >> 16);
}

__device__ __forceinline__ s16x8 cvt8(f32x4 lo, f32x4 hi) {
    s16x8 r;
    r[0] = f2bf(lo.x); r[1] = f2bf(lo.y); r[2] = f2bf(lo.z); r[3] = f2bf(lo.w);
    r[4] = f2bf(hi.x); r[5] = f2bf(hi.y); r[6] = f2bf(hi.z); r[7] = f2bf(hi.w);
    return r;
}

__device__ __forceinline__ f32x4 ntld(const float* p) {
    return __builtin_nontemporal_load(reinterpret_cast<const f32x4*>(p));
}

// h[b,s,d] = embed[x[b,s], d]  and  y = 0   (131072 threads exactly)
__global__ __launch_bounds__(256) void k_init(const int* __restrict__ x,
                                              const float* __restrict__ embed,
                                              float* __restrict__ h,
                                              float* __restrict__ y) {
    int tid = blockIdx.x * 256 + threadIdx.x;
    int bs = tid >> 6;
    int d  = tid & 63;
    h[tid] = embed[(size_t)x[bs] * ND + d];
    y[tid] = 0.f;
}

// eb[v][o] = bf16(embed[v][o])   (row-major, feeds MFMA B-frags directly)
__global__ __launch_bounds__(256) void k_cast(const float* __restrict__ embed,
                                              short* __restrict__ eb) {
    int tid = blockIdx.x * 256 + threadIdx.x;
    f32x4 v = *reinterpret_cast<const f32x4*>(embed + (size_t)tid * 4);
    s16x4 o;
    o.x = f2bf(v.x); o.y = f2bf(v.y); o.z = f2bf(v.z); o.w = f2bf(v.w);
    *reinterpret_cast<s16x4*>(eb + (size_t)tid * 4) = o;
}

// y[b,t,o] += sum_{s in chunk, s<=t} sum_d h[b,s,d] * K[t,s,d,o]
// Exact triangular launch, longest-job-first (t descending).
// R7: register double-buffer prefetch on the K stream (deeper in-flight pipe).
__global__ __launch_bounds__(256) void k_bilinear(const float* __restrict__ h,
                                                  const float* __restrict__ K,
                                                  float* __restrict__ y) {
    int L = (NCHUNK - 1) - (int)blockIdx.x;
    int g = 0;
    while (8 * (g + 1) * (g + 2) <= L) g++;       // group g = t>>4
    int rem = L - 8 * g * (g + 1);
    int tq  = rem / (g + 1);
    int t   = 16 * g + tq;
    int c   = rem - tq * (g + 1);
    int s0  = c * CH;
    int ns  = min(t + 1 - s0, CH);

    __shared__ float smem[NB * CH * ND]; // 32 KB; reused for reduction

    for (int i = threadIdx.x; i < NB * CH * ND; i += 256) {
        int b    = i >> 10;
        int rem2 = i & 1023;
        smem[i] = h[((size_t)b * NS + s0) * ND + rem2];
    }
    __syncthreads();

    int ot = threadIdx.x & 15;   // o-quad index
    int dg = threadIdx.x >> 4;   // d-group 0..15
    int o4 = ot * 4;
    int db = dg * 4;

    f32x4 acc[NB];
#pragma unroll
    for (int b = 0; b < NB; b++) acc[b] = (f32x4)(0.f);

    // per-thread K base for si=0
    const float* Kp = K + (size_t)t * NS * ND * ND + (size_t)s0 * ND * ND
                        + db * ND + o4;
    f32x4 c0 = ntld(Kp);
    f32x4 c1 = ntld(Kp + ND);
    f32x4 c2 = ntld(Kp + 2 * ND);
    f32x4 c3 = ntld(Kp + 3 * ND);

    for (int si = 0; si < ns - 1; si++) {
        const float* Kn = Kp + (size_t)(si + 1) * (ND * ND);
        f32x4 n0 = ntld(Kn);
        f32x4 n1 = ntld(Kn + ND);
        f32x4 n2 = ntld(Kn + 2 * ND);
        f32x4 n3 = ntld(Kn + 3 * ND);
#pragma unroll
        for (int b = 0; b < NB; b++) {
            const float* hb = smem + b * (CH * ND) + si * ND + db;
            acc[b] += hb[0] * c0;
            acc[b] += hb[1] * c1;
            acc[b] += hb[2] * c2;
            acc[b] += hb[3] * c3;
        }
        c0 = n0; c1 = n1; c2 = n2; c3 = n3;
    }
    {   // last si
        int si = ns - 1;
#pragma unroll
        for (int b = 0; b < NB; b++) {
            const float* hb = smem + b * (CH * ND) + si * ND + db;
            acc[b] += hb[0] * c0;
            acc[b] += hb[1] * c1;
            acc[b] += hb[2] * c2;
            acc[b] += hb[3] * c3;
        }
    }
    __syncthreads();

    f32x4* red = reinterpret_cast<f32x4*>(smem);
#pragma unroll
    for (int b = 0; b < NB; b++) red[(dg * NB + b) * 16 + ot] = acc[b];
    __syncthreads();

    if (threadIdx.x < 128) {
        int b = threadIdx.x >> 4;
        int o = threadIdx.x & 15;
        f32x4 s = (f32x4)(0.f);
#pragma unroll
        for (int gg = 0; gg < 16; gg++)
            s += red[(gg * NB + b) * 16 + o];
        float* yp = y + ((size_t)b * NS + t) * ND + o * 4;
        atomicAdd(yp + 0, s.x);
        atomicAdd(yp + 1, s.y);
        atomicAdd(yp + 2, s.z);
        atomicAdd(yp + 3, s.w);
    }
}

// out[bt, v] = sum_o y[bt, o] * E[v, o]  via bf16 MFMA (16x16x32, K=o)
__global__ __launch_bounds__(256) void k_logits_mfma(const float* __restrict__ y,
                                                     const short* __restrict__ eb,
                                                     float* __restrict__ out) {
    int bt0  = blockIdx.x * 16;
    int wave = threadIdx.x >> 6;
    int lane = threadIdx.x & 63;
    int m    = lane & 15;      // A row / B col / D col
    int kg   = lane >> 4;      // k-group of 8
    int vb0  = blockIdx.y * 1024 + wave * 256;

    const float* yrow = y + (size_t)(bt0 + m) * ND + kg * 8;
    f32x4 p0 = *reinterpret_cast<const f32x4*>(yrow);
    f32x4 p1 = *reinterpret_cast<const f32x4*>(yrow + 4);
    f32x4 p2 = *reinterpret_cast<const f32x4*>(yrow + 32);
    f32x4 p3 = *reinterpret_cast<const f32x4*>(yrow + 36);
    s16x8 a0 = cvt8(p0, p1);
    s16x8 a1 = cvt8(p2, p3);

    for (int nt = 0; nt < 16; nt++) {
        int v0 = vb0 + nt * 16;
        const short* erow = eb + (size_t)(v0 + m) * ND + kg * 8;
        s16x8 b0 = *reinterpret_cast<const s16x8*>(erow);
        s16x8 b1 = *reinterpret_cast<const s16x8*>(erow + 32);
        f32x4 cacc = (f32x4)(0.f);
        cacc = __builtin_amdgcn_mfma_f32_16x16x32_bf16(a0, b0, cacc, 0, 0, 0);
        cacc = __builtin_amdgcn_mfma_f32_16x16x32_bf16(a1, b1, cacc, 0, 0, 0);
        float* op = out + (size_t)(bt0 + kg * 4) * NV + v0 + m;
#pragma unroll
        for (int r = 0; r < 4; r++)
            __builtin_nontemporal_store(cacc[r], op + (size_t)r * NV);
    }
}

extern "C" void kernel_launch(void* const* d_in, const int* in_sizes, int n_in,
                              void* d_out, int out_size, void* d_ws, size_t ws_size,
                              hipStream_t stream) {
    const int*   x     = (const int*)d_in[0];
    const float* embed = (const float*)d_in[1];
    const float* K     = (const float*)d_in[2];
    float* out = (float*)d_out;

    float* h  = (float*)d_ws;          // 131072 f32 (512 KB)
    float* y  = h + NB * NS * ND;      // 131072 f32 (512 KB)
    short* eb = (short*)(y + NB * NS * ND); // 524288 bf16 (1 MB)

    k_init<<<dim3((NB * NS * ND) / 256), 256, 0, stream>>>(x, embed, h, y);
    k_cast<<<dim3((NV * ND) / 1024), 256, 0, stream>>>(embed, eb);
    k_bilinear<<<dim3(NCHUNK), 256, 0, stream>>>(h, K, y);
    k_logits_mfma<<<dim3((NB * NS) / 16, NV / 1024), 256, 0, stream>>>(y, eb, out);
}